// Round 1
// baseline (426.024 us; speedup 1.0000x reference)
//
#include <hip/hip_runtime.h>

// CTR-GC block, fp32.  N=64, C=64, T=256, V=25, O=64, R=8.
// Pipeline: k1_mean (xm = mean_t x) -> kA_x3 (x3 = W3@x+b3, into d_out)
//           -> k2_adj (adj = W4@(tanh-diff + tanh(softmax)) + 2*b4 + A, padded rows)
//           -> kB_out (out = x3 @ adj^T per (n,o), in-place over d_out)

#define N_ 64
#define C_ 64
#define T_ 256
#define V_ 25
#define O_ 64
#define R_ 8

#define TV_ (T_*V_)            // 6400
#define XM_FLOATS (N_*C_*V_)   // 102400
#define ADJ_STRIDE 28          // padded V so rows are 112B = 16B-aligned for float4

// ---------------------------------------------------------------- k1: xm = mean_t x
__global__ __launch_bounds__(256) void k1_mean(const float* __restrict__ x,
                                               float* __restrict__ xm) {
  __shared__ float xl[TV_];        // 25.6 KB
  __shared__ float red[4][V_];
  const int tid = threadIdx.x;
  const size_t base = (size_t)blockIdx.x * TV_;   // blockIdx.x = n*C + c
  // coalesced float4 stage of the [T,V] slab
  const float4* xg = reinterpret_cast<const float4*>(x + base);
  for (int i = tid; i < TV_/4; i += 256) {
    float4 v = xg[i];
    float* dst = &xl[4*i];
    dst[0]=v.x; dst[1]=v.y; dst[2]=v.z; dst[3]=v.w;
  }
  __syncthreads();
  // thread tid == time index t; banks spread since gcd(25,32)=1
  float s[V_];
  #pragma unroll
  for (int v = 0; v < V_; ++v) s[v] = xl[tid*V_ + v];
  #pragma unroll
  for (int v = 0; v < V_; ++v) {
    #pragma unroll
    for (int off = 32; off >= 1; off >>= 1) s[v] += __shfl_xor(s[v], off);
  }
  const int lane = tid & 63, w = tid >> 6;
  if (lane == 0) {
    #pragma unroll
    for (int v = 0; v < V_; ++v) red[w][v] = s[v];
  }
  __syncthreads();
  if (tid < V_) {
    float t = red[0][tid] + red[1][tid] + red[2][tid] + red[3][tid];
    xm[(size_t)blockIdx.x * V_ + tid] = t * (1.0f / T_);
  }
}

// ---------------------------------------------------------------- kA: x3 = W3@x + b3  (into d_out)
__global__ __launch_bounds__(256) void kA_x3(const float* __restrict__ x,
                                             const float* __restrict__ W3,
                                             const float* __restrict__ b3,
                                             float* __restrict__ x3) {
  const int n = blockIdx.y;
  const int col = blockIdx.x * 256 + threadIdx.x;   // flat (t,v) in [0,6400)
  const size_t nbase = (size_t)n * C_ * TV_;
  // 64 coalesced loads: this thread's column of x
  float xv[C_];
  #pragma unroll
  for (int c = 0; c < C_; ++c)
    xv[c] = x[nbase + (size_t)c * TV_ + col];
  // o loop: W3[o*64+c] is wave-uniform -> scalar loads
  for (int o = 0; o < O_; ++o) {
    const float* wr = W3 + o * C_;
    float a0 = 0.f, a1 = 0.f, a2 = 0.f, a3 = 0.f;
    #pragma unroll
    for (int c = 0; c < C_; c += 4) {
      a0 += wr[c+0] * xv[c+0];
      a1 += wr[c+1] * xv[c+1];
      a2 += wr[c+2] * xv[c+2];
      a3 += wr[c+3] * xv[c+3];
    }
    x3[nbase + (size_t)o * TV_ + col] = (a0 + a1) + (a2 + a3) + b3[o];
  }
}

// ---------------------------------------------------------------- k2: adj (padded rows)
__global__ __launch_bounds__(256) void k2_adj(
    const float* __restrict__ xm, const float* __restrict__ A,
    const float* __restrict__ W1, const float* __restrict__ b1,
    const float* __restrict__ W2, const float* __restrict__ b2,
    const float* __restrict__ W4, const float* __restrict__ b4,
    const float* __restrict__ W5, const float* __restrict__ b5,
    const float* __restrict__ w6p, const float* __restrict__ b6p,
    const float* __restrict__ w7p, const float* __restrict__ b7p,
    float* __restrict__ adjP) {
  __shared__ float xmL[C_ * V_];          // 1600
  __shared__ float p1[R_ * V_];           // 200
  __shared__ float p2[R_ * V_];
  __shared__ float pm[R_ * V_];
  __shared__ float dres[R_][V_][V_];      // 5000
  const int n = blockIdx.x, tid = threadIdx.x;

  for (int i = tid; i < C_ * V_; i += 256) xmL[i] = xm[(size_t)n * C_ * V_ + i];
  __syncthreads();

  // three R x V projections of xm (mean commutes with the 1x1 convs)
  for (int i = tid; i < 3 * R_ * V_; i += 256) {
    const int which = i / (R_ * V_), rem = i % (R_ * V_);
    const int r = rem / V_, v = rem % V_;
    const float* W = (which == 0) ? W1 : (which == 1) ? W2 : W5;
    const float* b = (which == 0) ? b1 : (which == 1) ? b2 : b5;
    float s = b[r];
    for (int c = 0; c < C_; ++c) s += W[r * C_ + c] * xmL[c * V_ + v];
    float* P = (which == 0) ? p1 : (which == 1) ? p2 : pm;
    P[rem] = s;
  }
  __syncthreads();

  // dres[r][u][v] = tanh(p1[r,u]-p2[r,v]) + tanh(softmax_v(5*q_u*k_v))
  if (tid < R_ * V_) {
    const int r = tid / V_, u = tid % V_;
    const float w6 = w6p[0], b6 = b6p[0], w7 = w7p[0], b7 = b7p[0];
    const float qu = w6 * pm[r * V_ + u] + b6;
    float e[V_];
    float mx = -INFINITY;
    #pragma unroll
    for (int v = 0; v < V_; ++v) {
      float a = 5.0f * qu * (w7 * pm[r * V_ + v] + b7);
      e[v] = a;
      mx = fmaxf(mx, a);
    }
    float ssum = 0.f;
    #pragma unroll
    for (int v = 0; v < V_; ++v) { float ev = expf(e[v] - mx); e[v] = ev; ssum += ev; }
    const float inv = 1.0f / ssum;
    const float p1u = p1[r * V_ + u];
    #pragma unroll
    for (int v = 0; v < V_; ++v) {
      float res = tanhf(e[v] * inv);
      float dv  = tanhf(p1u - p2[r * V_ + v]);
      dres[r][u][v] = dv + res;
    }
  }
  __syncthreads();

  // adj[o,u,v] = sum_r W4[o,r]*dres + 2*b4[o] + A[u,v], padded row stride 28
  for (int i = tid; i < O_ * V_; i += 256) {
    const int o = i / V_, u = i % V_;
    const float b4o2 = 2.0f * b4[o];
    float w4r[R_];
    #pragma unroll
    for (int r = 0; r < R_; ++r) w4r[r] = W4[o * R_ + r];
    float* dst = adjP + ((size_t)(n * O_ + o) * V_ + u) * ADJ_STRIDE;
    #pragma unroll
    for (int v = 0; v < V_; ++v) {
      float s = b4o2 + A[u * V_ + v];
      #pragma unroll
      for (int r = 0; r < R_; ++r) s += w4r[r] * dres[r][u][v];
      dst[v] = s;
    }
  }
}

// ---------------------------------------------------------------- kB: out = x3 @ adj^T (in place)
__global__ __launch_bounds__(256) void kB_out(float* __restrict__ x3,   // == d_out
                                              const float* __restrict__ adjP) {
  __shared__ float tl[T_ * 26];                    // 26.6 KB, stride 26 breaks pow2 banks
  __shared__ __align__(16) float adjL[V_ * ADJ_STRIDE];  // 700 floats
  const int o = blockIdx.x, n = blockIdx.y;
  const int tid = threadIdx.x;
  float* g = x3 + (size_t)(n * O_ + o) * TV_;

  // stage this (n,o) x3 tile [256 t x 25 v] -> LDS (coalesced f4 read, scatter write)
  const float4* g4 = reinterpret_cast<const float4*>(g);
  for (int i = tid; i < TV_/4; i += 256) {
    float4 v = g4[i];
    const int f = 4 * i;
    #pragma unroll
    for (int e = 0; e < 4; ++e) {
      const int fe = f + e;
      tl[(fe / V_) * 26 + (fe % V_)] = (&v.x)[e];
    }
  }
  // stage adj rows (700 floats = 175 float4)
  if (tid < 175) {
    float4 a = reinterpret_cast<const float4*>(adjP + (size_t)(n * O_ + o) * (V_ * ADJ_STRIDE))[tid];
    float* d = &adjL[4 * tid];
    d[0]=a.x; d[1]=a.y; d[2]=a.z; d[3]=a.w;
  }
  __syncthreads();

  // thread = t row
  float xr[V_];
  #pragma unroll
  for (int v = 0; v < V_; ++v) xr[v] = tl[tid * 26 + v];
  float orr[V_];
  #pragma unroll
  for (int u = 0; u < V_; ++u) {
    const float* ar = &adjL[u * ADJ_STRIDE];       // 16B-aligned (u*112B)
    float s = 0.f;
    #pragma unroll
    for (int j = 0; j < 6; ++j) {                  // v = 0..23 via float4 broadcast reads
      float4 a = *reinterpret_cast<const float4*>(ar + 4 * j);
      s += a.x * xr[4*j] + a.y * xr[4*j+1] + a.z * xr[4*j+2] + a.w * xr[4*j+3];
    }
    s += ar[24] * xr[24];
    orr[u] = s;
  }
  __syncthreads();                                  // all x3 reads from tl done
  #pragma unroll
  for (int u = 0; u < V_; ++u) tl[tid * 26 + u] = orr[u];
  __syncthreads();
  // coalesced f4 flush back over the same global tile
  for (int i = tid; i < TV_/4; i += 256) {
    const int f = 4 * i;
    float4 v;
    #pragma unroll
    for (int e = 0; e < 4; ++e) {
      const int fe = f + e;
      (&v.x)[e] = tl[(fe / V_) * 26 + (fe % V_)];
    }
    reinterpret_cast<float4*>(g)[i] = v;
  }
}

// ---------------------------------------------------------------- launch
extern "C" void kernel_launch(void* const* d_in, const int* in_sizes, int n_in,
                              void* d_out, int out_size, void* d_ws, size_t ws_size,
                              hipStream_t stream) {
  const float* x  = (const float*)d_in[0];
  const float* A  = (const float*)d_in[1];
  const float* W1 = (const float*)d_in[2];
  const float* b1 = (const float*)d_in[3];
  const float* W2 = (const float*)d_in[4];
  const float* b2 = (const float*)d_in[5];
  const float* W3 = (const float*)d_in[6];
  const float* b3 = (const float*)d_in[7];
  const float* W4 = (const float*)d_in[8];
  const float* b4 = (const float*)d_in[9];
  const float* W5 = (const float*)d_in[10];
  const float* b5 = (const float*)d_in[11];
  const float* w6 = (const float*)d_in[12];
  const float* b6 = (const float*)d_in[13];
  const float* w7 = (const float*)d_in[14];
  const float* b7 = (const float*)d_in[15];
  float* out  = (float*)d_out;
  float* xm   = (float*)d_ws;            // 102,400 f = 0.41 MB
  float* adjP = xm + XM_FLOATS;          // 2,867,200 f = 11.5 MB  (ws total ~11.9 MB)

  k1_mean<<<dim3(N_ * C_), 256, 0, stream>>>(x, xm);
  kA_x3 <<<dim3(TV_ / 256, N_), 256, 0, stream>>>(x, W3, b3, out);
  k2_adj<<<dim3(N_), 256, 0, stream>>>(xm, A, W1, b1, W2, b2, W4, b4, W5, b5,
                                       w6, b6, w7, b7, adjP);
  kB_out<<<dim3(O_, N_), 256, 0, stream>>>(out, adjP);
}